// Round 9
// baseline (226.870 us; speedup 1.0000x reference)
//
#include <hip/hip_runtime.h>
#include <hip/hip_bf16.h>
#include <cstdint>
#include <cstddef>

// B=4,G=64,N=256,C=256,HEAD=8,HD=32
// out = softmax((q@wq+bq)(k@wk+bk)^T / sqrt(32)) @ (v@wv+bv) @ wo + bo
// Round 9: PERSISTENT GEMM. 768 blocks (3/CU resident, no redispatch).
//   Block owns (op, 64-col n-tile, m-group): weight tile staged ONCE (full K,
//   R7 0-conflict layout); streams 8 panels x 8 K-chunks in one continuous
//   2-phase pipeline (issue A(g+1) -> compute(g) -> cvt/write -> 1 barrier).
//   Epilogue: operand-swapped MFMA (D = 4 consecutive COLS per reg) ->
//   vectorized s4/f4 stores.
// ws (bf16): Qb | Kb | Vb | WT(4x256x256) ; ctx aliases Qb.

typedef __attribute__((ext_vector_type(4))) float f4;
typedef __attribute__((ext_vector_type(8))) short s8;
typedef __attribute__((ext_vector_type(4))) short s4;
typedef unsigned short u16;

#define AS1 __attribute__((address_space(1)))
#define AS3 __attribute__((address_space(3)))

static constexpr int CD = 256;

__device__ __forceinline__ u16 f2bf(float f) {
    __hip_bfloat16 h = __float2bfloat16(f);   // RNE
    return *reinterpret_cast<u16*>(&h);
}

__device__ __forceinline__ void gload_lds16(const void* g, void* l) {
    __builtin_amdgcn_global_load_lds((const AS1 uint32_t*)g, (AS3 uint32_t*)l, 16, 0, 0);
}

// ---------------- prep: WT[n][k] = W[k][n] as bf16; wq pre-scaled by qs ------
__global__ __launch_bounds__(256) void prep_k(const float* __restrict__ wq,
                                              const float* __restrict__ wk,
                                              const float* __restrict__ wv,
                                              const float* __restrict__ wo,
                                              u16* __restrict__ WT, float qs)
{
    const int bx = blockIdx.x;                 // 64 blocks: 4 weights x 16 tiles
    const int wsel = bx >> 4, tl = bx & 15;
    const int k0 = (tl & 3) * 64, n0 = (tl >> 2) * 64;
    const float* W = wsel == 0 ? wq : wsel == 1 ? wk : wsel == 2 ? wv : wo;
    const float scale = wsel == 0 ? qs : 1.0f;
    u16* dst = WT + (size_t)wsel * 65536;
    __shared__ float T[64][65];
    const int t = threadIdx.x;
    const int rr = t >> 4, c0 = (t & 15) * 4;
    #pragma unroll
    for (int i = 0; i < 4; ++i) {
        int r = i * 16 + rr;
        f4 f = *(const f4*)(W + (size_t)(k0 + r) * CD + n0 + c0);
        #pragma unroll
        for (int j = 0; j < 4; ++j) T[c0 + j][r] = f[j] * scale;
    }
    __syncthreads();
    #pragma unroll
    for (int i = 0; i < 4; ++i) {
        int n = i * 16 + rr;
        s4 h;
        #pragma unroll
        for (int j = 0; j < 4; ++j) h[j] = (short)f2bf(T[n][c0 + j]);
        *(s4*)(dst + (size_t)(n0 + n) * CD + k0 + c0) = h;
    }
}

// ---------------- persistent GEMM body --------------------------------------
// Block: fixed (n0, mg). Streams npan panels (m0 = (mg + p*mstride)*128) of
// 128 rows x 64 cols, K chunked by 32. 4 waves, wave w = rows w*32..+31.
// As[2]: [128][32] bf16, elem col ^= ((row>>1)&3)<<3. Bs: R7 full-K layout.
template<bool A_F32, bool OUT_F32>
__device__ __forceinline__ void gemm_persist(const void* __restrict__ Ain,
                                             const u16* __restrict__ Wt,
                                             const float* __restrict__ bias,
                                             float escale, void* __restrict__ Out,
                                             int n0, int mg, int npan, int mstride)
{
    __shared__ u16 Bs[4][64 * 64];   // 32 KB, full K
    __shared__ u16 As[2][128 * 32];  // 16 KB, dbuf chunks
    const int t = threadIdx.x, lane = t & 63, w = t >> 6;
    const int lr = lane & 15, lkg = lane >> 4;
    const int bc = lane >> 3, bcol = (lane & 7) * 8;
    const int NG = npan * 8;

    // ---- stage B once (R7 layout, 0 conflicts measured) ----
    #pragma unroll
    for (int ck = 0; ck < 4; ++ck)
        #pragma unroll
        for (int j = 0; j < 2; ++j) {
            int c = j * 4 + w, row = c * 8 + bc, col = bcol ^ ((row & 7) << 3);
            gload_lds16(Wt + (size_t)(n0 + row) * CD + ck * 64 + col,
                        &Bs[ck][c * 512 + lane * 8]);
        }

    const float* Af = (const float*)Ain;
    const u16*  Ab = (const u16*)Ain;

    f4 rA0[4], rA1[4];   // two named prefetch sets (static indexing)

    // issue chunk-g A loads. fp32: coalesced f4 into regs. bf16: gload_lds.
    auto issue0 = [&](int g) {
        int p = g >> 3, k0 = (g & 7) * 32;
        size_t m0 = (size_t)(mg + p * mstride) * 128;
        if constexpr (A_F32) {
            #pragma unroll
            for (int j = 0; j < 4; ++j) {
                int ch = j * 256 + t, row = ch >> 3, c16 = ch & 7;
                rA0[j] = *(const f4*)(Af + (m0 + row) * CD + k0 + c16 * 4);
            }
        } else {
            #pragma unroll
            for (int j = 0; j < 2; ++j) {
                int rb = (w * 2 + j) * 16;
                int row = rb + (lane >> 2), c0 = (lane & 3) * 8;
                int scol = c0 ^ (((row >> 1) & 3) << 3);
                gload_lds16(Ab + (m0 + row) * CD + k0 + scol,
                            &As[0][rb * 32 + lane * 8]);
            }
        }
    };
    auto issue1 = [&](int g) {
        int p = g >> 3, k0 = (g & 7) * 32;
        size_t m0 = (size_t)(mg + p * mstride) * 128;
        if constexpr (A_F32) {
            #pragma unroll
            for (int j = 0; j < 4; ++j) {
                int ch = j * 256 + t, row = ch >> 3, c16 = ch & 7;
                rA1[j] = *(const f4*)(Af + (m0 + row) * CD + k0 + c16 * 4);
            }
        } else {
            #pragma unroll
            for (int j = 0; j < 2; ++j) {
                int rb = (w * 2 + j) * 16;
                int row = rb + (lane >> 2), c0 = (lane & 3) * 8;
                int scol = c0 ^ (((row >> 1) & 3) << 3);
                gload_lds16(Ab + (m0 + row) * CD + k0 + scol,
                            &As[1][rb * 32 + lane * 8]);
            }
        }
    };
    auto write0 = [&]() {   // fp32 only: cvt + swizzled ds_write -> As[0]
        if constexpr (A_F32) {
            #pragma unroll
            for (int j = 0; j < 4; ++j) {
                int ch = j * 256 + t, row = ch >> 3, c16 = ch & 7;
                s4 h;
                #pragma unroll
                for (int i = 0; i < 4; ++i) h[i] = (short)f2bf(rA0[j][i]);
                *(s4*)&As[0][row * 32 + ((c16 * 4) ^ (((row >> 1) & 3) << 3))] = h;
            }
        }
    };
    auto write1 = [&]() {
        if constexpr (A_F32) {
            #pragma unroll
            for (int j = 0; j < 4; ++j) {
                int ch = j * 256 + t, row = ch >> 3, c16 = ch & 7;
                s4 h;
                #pragma unroll
                for (int i = 0; i < 4; ++i) h[i] = (short)f2bf(rA1[j][i]);
                *(s4*)&As[1][row * 32 + ((c16 * 4) ^ (((row >> 1) & 3) << 3))] = h;
            }
        }
    };

    f4 acc[2][4] = {};

    // ---- prologue: chunk 0 into buf 0 ----
    issue0(0);
    write0();            // fp32: waits only its own loads (counted)
    __syncthreads();     // B + As[0] ready

    for (int p = 0; p < npan; ++p) {
        const size_t m0 = (size_t)(mg + p * mstride) * 128;
        #pragma unroll
        for (int c = 0; c < 8; ++c) {
            const int g = p * 8 + c;
            const bool haveNext = (g + 1 < NG);
            // 1. issue next chunk into the other set/buffer
            if (haveNext) { if ((c & 1) == 0) issue1(g + 1); else issue0(g + 1); }
            // 2. compute chunk g from As[c&1] + Bs
            {
                const int buf = c & 1;
                const int ck = (g >> 1) & 3, kk = (g & 1) * 32;
                s8 afr[2], bfr[4];
                #pragma unroll
                for (int m = 0; m < 2; ++m) {
                    int row = w * 32 + m * 16 + lr;
                    afr[m] = *(const s8*)&As[buf][row * 32 +
                                 ((lkg * 8) ^ (((row >> 1) & 3) << 3))];
                }
                #pragma unroll
                for (int n = 0; n < 4; ++n) {
                    int R = n * 16 + lr;
                    bfr[n] = *(const s8*)&Bs[ck][R * 64 +
                                 ((kk + lkg * 8) ^ ((R & 7) << 3))];
                }
                // swapped operands: D[reg r] = C[row][col0 + r]
                #pragma unroll
                for (int m = 0; m < 2; ++m)
                    #pragma unroll
                    for (int n = 0; n < 4; ++n)
                        acc[m][n] = __builtin_amdgcn_mfma_f32_16x16x32_bf16(
                            bfr[n], afr[m], acc[m][n], 0, 0, 0);
            }
            // 3. fp32 path: cvt+write next chunk (loads have been in flight)
            if (haveNext) { if ((c & 1) == 0) write1(); else write0(); }
            // 4. panel epilogue: vectorized stores (4 cols/reg after swap)
            if (c == 7) {
                #pragma unroll
                for (int m = 0; m < 2; ++m)
                    #pragma unroll
                    for (int n = 0; n < 4; ++n) {
                        int col0 = n0 + n * 16 + lkg * 4;
                        int row = (int)m0 + w * 32 + m * 16 + lr;
                        f4 bb = *(const f4*)&bias[col0];
                        f4 vv;
                        #pragma unroll
                        for (int r = 0; r < 4; ++r)
                            vv[r] = acc[m][n][r] + bb[r] * escale;
                        if constexpr (OUT_F32) {
                            *(f4*)&((float*)Out)[(size_t)row * CD + col0] = vv;
                        } else {
                            s4 h;
                            #pragma unroll
                            for (int r = 0; r < 4; ++r) h[r] = (short)f2bf(vv[r]);
                            *(s4*)&((u16*)Out)[(size_t)row * CD + col0] = h;
                        }
                        acc[m][n] = f4{0.f, 0.f, 0.f, 0.f};
                    }
            }
            __syncthreads();
        }
    }
}

// 768 blocks: op = b>>8; n-tile = (b>>6)&3; m-group = b&63 (siblings +64 -> same XCD)
__global__ __launch_bounds__(256, 3) void gemmqkv_k(const float* q, const float* k,
        const float* v, const u16* WT, const float* bq, const float* bk,
        const float* bv, float qs, u16* Qb, u16* Kb, u16* Vb)
{
    const int b = blockIdx.x;
    const int op = b >> 8, r = b & 255;
    const int n0 = ((r >> 6) & 3) * 64, mg = r & 63;
    const float* A    = op == 0 ? q  : op == 1 ? k  : v;
    const u16*   Wt   = WT + (size_t)op * 65536;
    const float* bias = op == 0 ? bq : op == 1 ? bk : bv;
    u16*         Out  = op == 0 ? Qb : op == 1 ? Kb : Vb;
    gemm_persist<true, false>(A, Wt, bias, op == 0 ? qs : 1.0f, Out,
                              n0, mg, 8, 64);
}

// 512 blocks: n-tile = b>>7; m-group = b&127 (siblings +128 -> same XCD)
__global__ __launch_bounds__(256, 2) void gemmo_k(const u16* Cx, const u16* WT,
                                                  const float* bo, float* out)
{
    const int b = blockIdx.x;
    const int n0 = (b >> 7) * 64, mg = b & 127;
    gemm_persist<false, true>(Cx, WT, bo, 1.0f, out, n0, mg, 4, 128);
}

// ---------------- attn: one block per (b,g,h); 4 waves x 64 q-rows ----------
// Q pre-scaled by log2e/sqrt(hd) (folded into Wq) -> softmax via exp2.
__global__ __launch_bounds__(256, 3) void attn_k(const u16* Qb,
                                                 const u16* __restrict__ Kb,
                                                 const u16* __restrict__ Vb,
                                                 u16* Ctx)   // Ctx aliases Qb!
{
    __shared__ u16 Ks[256 * 32];       // swizzled rows of 32 elems, 16 KB
    __shared__ u16 Vt[32][260];        // [d][krow], 16.25 KB
    __shared__ u16 Ps[4][16][132];     // per-wave half-strip, 16.5 KB
    const int d = blockIdx.x;          // h*256 + bg: all h of a (b,g) same XCD
    const int bg = d & 255, h = d >> 8;
    const size_t base = (size_t)bg * (256 * 256) + h * 32;
    const int t = threadIdx.x, lane = t & 63, w = t >> 6;
    const int lr = lane & 15, lk = (lane >> 4) * 8;
    const int orow = (lane >> 4) * 4;

    // stage K (swizzled global_load_lds: slot ^= ((row>>1)&3)<<3)
    #pragma unroll
    for (int j = 0; j < 4; ++j) {
        int c = j * 4 + w;
        int row = c * 16 + (lane >> 2);
        int col = ((lane & 3) * 8) ^ (((row >> 1) & 3) << 3);
        gload_lds16(Kb + base + (size_t)row * CD + col, &Ks[c * 512 + lane * 8]);
    }
    // stage V transposed: each thread one 4x8 block, vectorized s4 column writes
    {
        int n0 = (t >> 2) * 4, c0 = (t & 3) * 8;
        const u16* vp = Vb + base + (size_t)n0 * CD + c0;
        s8 r0 = *(const s8*)(vp);
        s8 r1 = *(const s8*)(vp + CD);
        s8 r2 = *(const s8*)(vp + 2 * CD);
        s8 r3 = *(const s8*)(vp + 3 * CD);
        #pragma unroll
        for (int i = 0; i < 8; ++i) {
            s4 cv = { r0[i], r1[i], r2[i], r3[i] };
            *(s4*)&Vt[c0 + i][n0] = cv;
        }
    }
    // hoist all Q fragments (must precede any Ctx write: Ctx aliases Qb)
    s8 aq[4];
    #pragma unroll
    for (int m = 0; m < 4; ++m)
        aq[m] = *(const s8*)(Qb + base + (size_t)(w * 64 + m * 16 + lr) * CD + lk);

    __syncthreads();

    const int myslot = lk ^ (((lr >> 1) & 3) << 3);
    const f4 zero = {0.f, 0.f, 0.f, 0.f};

    #pragma unroll
    for (int m = 0; m < 4; ++m) {
        // S = Q K^T  (16 q-rows x 256 k)
        f4 s[16];
        #pragma unroll
        for (int j = 0; j < 16; ++j) {
            s8 bk = *(const s8*)&Ks[(j * 16 + lr) * 32 + myslot];
            s[j] = __builtin_amdgcn_mfma_f32_16x16x32_bf16(aq[m], bk, zero, 0, 0, 0);
        }
        // softmax over k (base-2 domain; scale folded into Q)
        float mrow[4] = {-3.0e38f, -3.0e38f, -3.0e38f, -3.0e38f};
        #pragma unroll
        for (int j = 0; j < 16; ++j)
            #pragma unroll
            for (int r = 0; r < 4; ++r) mrow[r] = fmaxf(mrow[r], s[j][r]);
        #pragma unroll
        for (int dd = 1; dd < 16; dd <<= 1)
            #pragma unroll
            for (int r = 0; r < 4; ++r) mrow[r] = fmaxf(mrow[r], __shfl_xor(mrow[r], dd));
        float lsum[4] = {0.f, 0.f, 0.f, 0.f};
        #pragma unroll
        for (int j = 0; j < 16; ++j)
            #pragma unroll
            for (int r = 0; r < 4; ++r) {
                float p = exp2f(s[j][r] - mrow[r]);
                s[j][r] = p;
                lsum[r] += p;
            }
        #pragma unroll
        for (int dd = 1; dd < 16; dd <<= 1)
            #pragma unroll
            for (int r = 0; r < 4; ++r) lsum[r] += __shfl_xor(lsum[r], dd);

        // PV in two halves through per-wave Ps strip (no barrier: wave-local)
        f4 o0 = zero, o1 = zero;
        #pragma unroll
        for (int half = 0; half < 2; ++half) {
            #pragma unroll
            for (int j = 0; j < 8; ++j)
                #pragma unroll
                for (int r = 0; r < 4; ++r)
                    Ps[w][orow + r][j * 16 + lr] = f2bf(s[half * 8 + j][r]);
            #pragma unroll
            for (int kk = 0; kk < 4; ++kk) {
                s8 ap  = *(const s8*)&Ps[w][lr][kk * 32 + lk];
                s8 bv0 = *(const s8*)&Vt[lr][(half * 4 + kk) * 32 + lk];
                s8 bv1 = *(const s8*)&Vt[16 + lr][(half * 4 + kk) * 32 + lk];
                o0 = __builtin_amdgcn_mfma_f32_16x16x32_bf16(ap, bv0, o0, 0, 0, 0);
                o1 = __builtin_amdgcn_mfma_f32_16x16x32_bf16(ap, bv1, o1, 0, 0, 0);
            }
        }
        // store ctx rows (writes into Qb region owned by this wave's rows)
        #pragma unroll
        for (int r = 0; r < 4; ++r) {
            float inv = __builtin_amdgcn_rcpf(lsum[r]);
            int row = w * 64 + m * 16 + orow + r;
            Ctx[base + (size_t)row * CD + lr]      = f2bf(o0[r] * inv);
            Ctx[base + (size_t)row * CD + 16 + lr] = f2bf(o1[r] * inv);
        }
    }
}

extern "C" void kernel_launch(void* const* d_in, const int* in_sizes, int n_in,
                              void* d_out, int out_size, void* d_ws, size_t ws_size,
                              hipStream_t stream) {
    const float* q  = (const float*)d_in[0];
    const float* k  = (const float*)d_in[1];
    const float* v  = (const float*)d_in[2];
    const float* wq = (const float*)d_in[3];
    const float* bq = (const float*)d_in[4];
    const float* wk = (const float*)d_in[5];
    const float* bk = (const float*)d_in[6];
    const float* wv = (const float*)d_in[7];
    const float* bv = (const float*)d_in[8];
    const float* wo = (const float*)d_in[9];
    const float* bo = (const float*)d_in[10];
    float* out = (float*)d_out;

    const size_t E = (size_t)65536 * 256;
    u16* Qb = (u16*)d_ws;
    u16* Kb = Qb + E;
    u16* Vb = Kb + E;
    u16* WT = Vb + E;          // 4*65536 u16 = 512 KB; total ws = 96.5 MB
    u16* Cx = Qb;              // ctx aliases Qb (safe: per-wave hoisted Q reads)

    const float qs = (1.0f / (sqrtf(32.0f) + 1e-8f)) * 1.4426950408889634f;

    prep_k<<<64, 256, 0, stream>>>(wq, wk, wv, wo, WT, qs);
    gemmqkv_k<<<768, 256, 0, stream>>>(q, k, v, WT, bq, bk, bv, qs, Qb, Kb, Vb);
    attn_k<<<2048, 256, 0, stream>>>(Qb, Kb, Vb, Cx);
    gemmo_k<<<512, 256, 0, stream>>>(Cx, WT + 3 * 65536, bo, out);
}

// Round 10
// 183.804 us; speedup vs baseline: 1.2343x; 1.2343x over previous
//
#include <hip/hip_runtime.h>
#include <hip/hip_bf16.h>
#include <cstdint>
#include <cstddef>

// B=4,G=64,N=256,C=256,HEAD=8,HD=32
// out = softmax((q@wq+bq)(k@wk+bk)^T / sqrt(32)) @ (v@wv+bv) @ wo + bo
// Round 10: R3-structure GEMM with 4 blocks/CU (single-buf BK=64, 32KB LDS,
// launch_bounds(256,4)), reg-prefetch of next A-chunk across compute phase,
// swapped-operand MFMA epilogue (vectorized stores). attn/prep unchanged.
// ws (bf16): Qb | Kb | Vb | WT(4x256x256) ; ctx aliases Qb.

typedef __attribute__((ext_vector_type(4))) float f4;
typedef __attribute__((ext_vector_type(8))) short s8;
typedef __attribute__((ext_vector_type(4))) short s4;
typedef unsigned short u16;

#define AS1 __attribute__((address_space(1)))
#define AS3 __attribute__((address_space(3)))

static constexpr int CD = 256;

__device__ __forceinline__ u16 f2bf(float f) {
    __hip_bfloat16 h = __float2bfloat16(f);   // RNE
    return *reinterpret_cast<u16*>(&h);
}

__device__ __forceinline__ void gload_lds16(const void* g, void* l) {
    __builtin_amdgcn_global_load_lds((const AS1 uint32_t*)g, (AS3 uint32_t*)l, 16, 0, 0);
}

// ---------------- prep: WT[n][k] = W[k][n] as bf16; wq pre-scaled by qs ------
__global__ __launch_bounds__(256) void prep_k(const float* __restrict__ wq,
                                              const float* __restrict__ wk,
                                              const float* __restrict__ wv,
                                              const float* __restrict__ wo,
                                              u16* __restrict__ WT, float qs)
{
    const int bx = blockIdx.x;                 // 64 blocks: 4 weights x 16 tiles
    const int wsel = bx >> 4, tl = bx & 15;
    const int k0 = (tl & 3) * 64, n0 = (tl >> 2) * 64;
    const float* W = wsel == 0 ? wq : wsel == 1 ? wk : wsel == 2 ? wv : wo;
    const float scale = wsel == 0 ? qs : 1.0f;
    u16* dst = WT + (size_t)wsel * 65536;
    __shared__ float T[64][65];
    const int t = threadIdx.x;
    const int rr = t >> 4, c0 = (t & 15) * 4;
    #pragma unroll
    for (int i = 0; i < 4; ++i) {
        int r = i * 16 + rr;
        f4 f = *(const f4*)(W + (size_t)(k0 + r) * CD + n0 + c0);
        #pragma unroll
        for (int j = 0; j < 4; ++j) T[c0 + j][r] = f[j] * scale;
    }
    __syncthreads();
    #pragma unroll
    for (int i = 0; i < 4; ++i) {
        int n = i * 16 + rr;
        s4 h;
        #pragma unroll
        for (int j = 0; j < 4; ++j) h[j] = (short)f2bf(T[n][c0 + j]);
        *(s4*)(dst + (size_t)(n0 + n) * CD + k0 + c0) = h;
    }
}

// ---------------- GEMM: Out[m0:+128][n0:+128] = A @ WT^T + bias*escale ------
// Single-buffered [128][64] bf16 LDS per operand (32 KB total -> 4 blocks/CU).
// XOR swizzle col ^= (row&7)<<3 (R6: measured 0 conflicts).
template<bool A_F32, bool OUT_F32>
__device__ __forceinline__ void gemm_body(const void* __restrict__ Ain,
                                          const u16* __restrict__ Wt,
                                          const float* __restrict__ bias,
                                          float escale, void* __restrict__ Out,
                                          int d)
{
    __shared__ u16 As[128 * 64];
    __shared__ u16 Bs[128 * 64];
    const int t = threadIdx.x, lane = t & 63, w = t >> 6;
    const int n0 = (d >> 9) * 128;       // (d, d+512) share m0 -> same XCD
    const int m0 = (d & 511) * 128;
    const int wr = (w >> 1) * 64, wc = (w & 1) * 64;
    const int lr = lane & 15, lkg = lane >> 4;
    const int lk = lkg * 8;
    const int bc = lane >> 3, bcol = (lane & 7) * 8;

    f4 acc[4][4] = {};
    f4 pa[8];   // fp32 A prefetch regs (static indexing only)

    auto stageB = [&](int k0) {
        #pragma unroll
        for (int j = 0; j < 4; ++j) {
            int c = j * 4 + w;
            int row = c * 8 + bc;
            int col = bcol ^ ((row & 7) << 3);
            gload_lds16(Wt + (size_t)(n0 + row) * CD + k0 + col,
                        &Bs[c * 512 + lane * 8]);
        }
    };
    auto stageA16 = [&](int k0) {
        const u16* A = (const u16*)Ain;
        #pragma unroll
        for (int j = 0; j < 4; ++j) {
            int c = j * 4 + w;
            int row = c * 8 + bc;
            int col = bcol ^ ((row & 7) << 3);
            gload_lds16(A + (size_t)(m0 + row) * CD + k0 + col,
                        &As[c * 512 + lane * 8]);
        }
    };
    auto loadA = [&](int k0) {           // coalesced fp32 loads into regs
        const float* A = (const float*)Ain;
        #pragma unroll
        for (int j = 0; j < 4; ++j) {
            int ch = t + j * 256;
            int r = ch >> 3, c8 = ch & 7;
            const float* src = A + (size_t)(m0 + r) * CD + k0 + c8 * 8;
            pa[2 * j]     = *(const f4*)src;
            pa[2 * j + 1] = *(const f4*)(src + 4);
        }
    };
    auto writeA = [&]() {                // cvt + swizzled ds_write
        #pragma unroll
        for (int j = 0; j < 4; ++j) {
            int ch = t + j * 256;
            int r = ch >> 3, c8 = ch & 7;
            s8 h;
            #pragma unroll
            for (int i = 0; i < 4; ++i) {
                h[i]     = (short)f2bf(pa[2 * j][i]);
                h[i + 4] = (short)f2bf(pa[2 * j + 1][i]);
            }
            *(s8*)&As[r * 64 + ((c8 * 8) ^ ((r & 7) << 3))] = h;
        }
    };
    auto compute = [&]() {
        #pragma unroll
        for (int kk = 0; kk < 64; kk += 32) {
            s8 a[4], b[4];
            #pragma unroll
            for (int m = 0; m < 4; ++m) {
                int R = wr + m * 16 + lr;
                a[m] = *(const s8*)&As[R * 64 + ((kk + lk) ^ ((R & 7) << 3))];
            }
            #pragma unroll
            for (int n = 0; n < 4; ++n) {
                int R = wc + n * 16 + lr;
                b[n] = *(const s8*)&Bs[R * 64 + ((kk + lk) ^ ((R & 7) << 3))];
            }
            // swapped operands: D reg r = out[row][col0 + r] (R9-verified)
            #pragma unroll
            for (int m = 0; m < 4; ++m)
                #pragma unroll
                for (int n = 0; n < 4; ++n)
                    acc[m][n] = __builtin_amdgcn_mfma_f32_16x16x32_bf16(
                        b[n], a[m], acc[m][n], 0, 0, 0);
        }
    };

    // prologue: stage tile 0
    if constexpr (A_F32) { loadA(0); stageB(0); writeA(); }
    else { stageA16(0); stageB(0); }
    __syncthreads();

    #pragma unroll
    for (int ti = 0; ti < 4; ++ti) {
        // next-step fp32 A loads: register-only, issued before compute so the
        // whole compute phase covers their HBM latency (no LDS hazard).
        if constexpr (A_F32) { if (ti < 3) loadA((ti + 1) * 64); }
        compute();
        __syncthreads();   // all waves done reading As/Bs for step ti
        if (ti < 3) {
            if constexpr (A_F32) { writeA(); stageB((ti + 1) * 64); }
            else { stageA16((ti + 1) * 64); stageB((ti + 1) * 64); }
            __syncthreads();   // tile ti+1 staged
        }
    }

    // epilogue (swapped layout): lane holds 4 consecutive cols per acc reg set
    #pragma unroll
    for (int m = 0; m < 4; ++m) {
        int row = m0 + wr + m * 16 + lr;
        #pragma unroll
        for (int n = 0; n < 4; ++n) {
            int col0 = n0 + wc + n * 16 + lkg * 4;
            f4 bb = *(const f4*)&bias[col0];
            f4 vv;
            #pragma unroll
            for (int r = 0; r < 4; ++r) vv[r] = acc[m][n][r] + bb[r] * escale;
            if constexpr (OUT_F32) {
                *(f4*)&((float*)Out)[(size_t)row * CD + col0] = vv;
            } else {
                s4 h;
                #pragma unroll
                for (int r = 0; r < 4; ++r) h[r] = (short)f2bf(vv[r]);
                *(s4*)&((u16*)Out)[(size_t)row * CD + col0] = h;
            }
        }
    }
}

__global__ __launch_bounds__(256, 4) void gemmqkv_k(const float* q, const float* k,
        const float* v, const u16* WT, const float* bq, const float* bk,
        const float* bv, float qs, u16* Qb, u16* Kb, u16* Vb)
{
    const int op = blockIdx.x >> 10;     // 1024 blocks per op (1024%8==0)
    const int d  = blockIdx.x & 1023;
    const float* A    = op == 0 ? q  : op == 1 ? k  : v;
    const u16*   Wt   = WT + (size_t)op * 65536;
    const float* bias = op == 0 ? bq : op == 1 ? bk : bv;
    u16*         Out  = op == 0 ? Qb : op == 1 ? Kb : Vb;
    gemm_body<true, false>(A, Wt, bias, op == 0 ? qs : 1.0f, Out, d);
}

__global__ __launch_bounds__(256, 4) void gemmo_k(const u16* Cx, const u16* WT,
                                                  const float* bo, float* out)
{
    gemm_body<false, true>(Cx, WT, bo, 1.0f, out, blockIdx.x);
}

// ---------------- attn: one block per (b,g,h); 4 waves x 64 q-rows ----------
// Q pre-scaled by log2e/sqrt(hd) (folded into Wq) -> softmax via exp2.
__global__ __launch_bounds__(256, 3) void attn_k(const u16* Qb,
                                                 const u16* __restrict__ Kb,
                                                 const u16* __restrict__ Vb,
                                                 u16* Ctx)   // Ctx aliases Qb!
{
    __shared__ u16 Ks[256 * 32];       // swizzled rows of 32 elems, 16 KB
    __shared__ u16 Vt[32][260];        // [d][krow], 16.25 KB
    __shared__ u16 Ps[4][16][132];     // per-wave half-strip, 16.5 KB
    const int d = blockIdx.x;          // h*256 + bg: all h of a (b,g) same XCD
    const int bg = d & 255, h = d >> 8;
    const size_t base = (size_t)bg * (256 * 256) + h * 32;
    const int t = threadIdx.x, lane = t & 63, w = t >> 6;
    const int lr = lane & 15, lk = (lane >> 4) * 8;
    const int orow = (lane >> 4) * 4;

    // stage K (swizzled global_load_lds: slot ^= ((row>>1)&3)<<3)
    #pragma unroll
    for (int j = 0; j < 4; ++j) {
        int c = j * 4 + w;
        int row = c * 16 + (lane >> 2);
        int col = ((lane & 3) * 8) ^ (((row >> 1) & 3) << 3);
        gload_lds16(Kb + base + (size_t)row * CD + col, &Ks[c * 512 + lane * 8]);
    }
    // stage V transposed: each thread one 4x8 block, vectorized s4 column writes
    {
        int n0 = (t >> 2) * 4, c0 = (t & 3) * 8;
        const u16* vp = Vb + base + (size_t)n0 * CD + c0;
        s8 r0 = *(const s8*)(vp);
        s8 r1 = *(const s8*)(vp + CD);
        s8 r2 = *(const s8*)(vp + 2 * CD);
        s8 r3 = *(const s8*)(vp + 3 * CD);
        #pragma unroll
        for (int i = 0; i < 8; ++i) {
            s4 cv = { r0[i], r1[i], r2[i], r3[i] };
            *(s4*)&Vt[c0 + i][n0] = cv;
        }
    }
    // hoist all Q fragments (must precede any Ctx write: Ctx aliases Qb)
    s8 aq[4];
    #pragma unroll
    for (int m = 0; m < 4; ++m)
        aq[m] = *(const s8*)(Qb + base + (size_t)(w * 64 + m * 16 + lr) * CD + lk);

    __syncthreads();

    const int myslot = lk ^ (((lr >> 1) & 3) << 3);
    const f4 zero = {0.f, 0.f, 0.f, 0.f};

    #pragma unroll
    for (int m = 0; m < 4; ++m) {
        // S = Q K^T  (16 q-rows x 256 k)
        f4 s[16];
        #pragma unroll
        for (int j = 0; j < 16; ++j) {
            s8 bk = *(const s8*)&Ks[(j * 16 + lr) * 32 + myslot];
            s[j] = __builtin_amdgcn_mfma_f32_16x16x32_bf16(aq[m], bk, zero, 0, 0, 0);
        }
        // softmax over k (base-2 domain; scale folded into Q)
        float mrow[4] = {-3.0e38f, -3.0e38f, -3.0e38f, -3.0e38f};
        #pragma unroll
        for (int j = 0; j < 16; ++j)
            #pragma unroll
            for (int r = 0; r < 4; ++r) mrow[r] = fmaxf(mrow[r], s[j][r]);
        #pragma unroll
        for (int dd = 1; dd < 16; dd <<= 1)
            #pragma unroll
            for (int r = 0; r < 4; ++r) mrow[r] = fmaxf(mrow[r], __shfl_xor(mrow[r], dd));
        float lsum[4] = {0.f, 0.f, 0.f, 0.f};
        #pragma unroll
        for (int j = 0; j < 16; ++j)
            #pragma unroll
            for (int r = 0; r < 4; ++r) {
                float p = exp2f(s[j][r] - mrow[r]);
                s[j][r] = p;
                lsum[r] += p;
            }
        #pragma unroll
        for (int dd = 1; dd < 16; dd <<= 1)
            #pragma unroll
            for (int r = 0; r < 4; ++r) lsum[r] += __shfl_xor(lsum[r], dd);

        // PV in two halves through per-wave Ps strip (no barrier: wave-local)
        f4 o0 = zero, o1 = zero;
        #pragma unroll
        for (int half = 0; half < 2; ++half) {
            #pragma unroll
            for (int j = 0; j < 8; ++j)
                #pragma unroll
                for (int r = 0; r < 4; ++r)
                    Ps[w][orow + r][j * 16 + lr] = f2bf(s[half * 8 + j][r]);
            #pragma unroll
            for (int kk = 0; kk < 4; ++kk) {
                s8 ap  = *(const s8*)&Ps[w][lr][kk * 32 + lk];
                s8 bv0 = *(const s8*)&Vt[lr][(half * 4 + kk) * 32 + lk];
                s8 bv1 = *(const s8*)&Vt[16 + lr][(half * 4 + kk) * 32 + lk];
                o0 = __builtin_amdgcn_mfma_f32_16x16x32_bf16(ap, bv0, o0, 0, 0, 0);
                o1 = __builtin_amdgcn_mfma_f32_16x16x32_bf16(ap, bv1, o1, 0, 0, 0);
            }
        }
        // store ctx rows (writes into Qb region owned by this wave's rows)
        #pragma unroll
        for (int r = 0; r < 4; ++r) {
            float inv = __builtin_amdgcn_rcpf(lsum[r]);
            int row = w * 64 + m * 16 + orow + r;
            Ctx[base + (size_t)row * CD + lr]      = f2bf(o0[r] * inv);
            Ctx[base + (size_t)row * CD + 16 + lr] = f2bf(o1[r] * inv);
        }
    }
}

extern "C" void kernel_launch(void* const* d_in, const int* in_sizes, int n_in,
                              void* d_out, int out_size, void* d_ws, size_t ws_size,
                              hipStream_t stream) {
    const float* q  = (const float*)d_in[0];
    const float* k  = (const float*)d_in[1];
    const float* v  = (const float*)d_in[2];
    const float* wq = (const float*)d_in[3];
    const float* bq = (const float*)d_in[4];
    const float* wk = (const float*)d_in[5];
    const float* bk = (const float*)d_in[6];
    const float* wv = (const float*)d_in[7];
    const float* bv = (const float*)d_in[8];
    const float* wo = (const float*)d_in[9];
    const float* bo = (const float*)d_in[10];
    float* out = (float*)d_out;

    const size_t E = (size_t)65536 * 256;
    u16* Qb = (u16*)d_ws;
    u16* Kb = Qb + E;
    u16* Vb = Kb + E;
    u16* WT = Vb + E;          // 4*65536 u16 = 512 KB; total ws = 96.5 MB
    u16* Cx = Qb;              // ctx aliases Qb (safe: per-wave hoisted Q reads)

    const float qs = (1.0f / (sqrtf(32.0f) + 1e-8f)) * 1.4426950408889634f;

    prep_k<<<64, 256, 0, stream>>>(wq, wk, wv, wo, WT, qs);
    gemmqkv_k<<<3072, 256, 0, stream>>>(q, k, v, WT, bq, bk, bv, qs, Qb, Kb, Vb);
    attn_k<<<2048, 256, 0, stream>>>(Qb, Kb, Vb, Cx);
    gemmo_k<<<1024, 256, 0, stream>>>(Cx, WT + 3 * 65536, bo, out);
}